// Round 8
// baseline (202.288 us; speedup 1.0000x reference)
//
#include <hip/hip_runtime.h>
#include <hip/hip_bf16.h>
#include <math.h>

#define N 512
#define NN (N*N)
#define D 128
#define DD (D*D)
#define ND (N*D)
#define LSTR 132   // LDS row stride (floats) for 128-wide tiles
#define CSTR 36    // LDS row stride for 32-wide c tile
#define NSLAB 18   // 17 s-chunk slabs (0..16) + W slab (17)

__device__ __forceinline__ float sigmoidf_(float x) { return 1.f / (1.f + expf(-x)); }

// ---------------- phase 1: per-token scalars, k/v/q, MLP fwd+bwd ----------------
__global__ __launch_bounds__(512) void k_phase1(
    const float* __restrict__ seq, const float* __restrict__ W_mem,
    const float* __restrict__ W_q, const float* __restrict__ W_kv,
    const float* __restrict__ W_mom, const float* __restrict__ W_step,
    const float* __restrict__ W_decay,
    float* __restrict__ Q, float* __restrict__ INS, float* __restrict__ ES,
    float* __restrict__ am, float* __restrict__ dec)
{
    __shared__ __align__(16) float s_seq[D], s_v[D], s_cur[D];
    __shared__ __align__(16) float s_h[4][D];
    __shared__ __align__(16) float s_part[4][D];
    __shared__ __align__(16) float s_p3[4][3][D];
    __shared__ float s_red[8];
    __shared__ float s_lr;

    const int t = blockIdx.x;
    const int tid = threadIdx.x;
    const int j = tid & 127;
    const int p = tid >> 7;
    const int i0 = p * 32;

    if (p == 0) s_seq[j] = seq[t * D + j];
    __syncthreads();

    float ps = 0.f;
    if (p == 1) ps = s_seq[j] * W_step[j];
    else if (p == 2) ps = s_seq[j] * W_mom[j];
    else if (p == 3) ps = s_seq[j] * W_decay[j];
#pragma unroll
    for (int off = 32; off > 0; off >>= 1) ps += __shfl_down(ps, off);
    if ((tid & 63) == 0) s_red[tid >> 6] = ps;
    __syncthreads();
    if (tid == 0) s_lr = s_red[2] + s_red[3];
    else if (tid == 1) am[t] = s_red[4] + s_red[5];
    else if (tid == 2) dec[t] = 1.f - sigmoidf_(s_red[6] + s_red[7]);

    float kp = 0.f, vp = 0.f, qp = 0.f;
#pragma unroll 8
    for (int ii = 0; ii < 32; ii++) {
        int i = i0 + ii;
        float si = s_seq[i];
        kp += si * W_kv[i * 256 + j];
        vp += si * W_kv[i * 256 + 128 + j];
        qp += si * W_q[i * 128 + j];
    }
    s_p3[p][0][j] = kp; s_p3[p][1][j] = vp; s_p3[p][2][j] = qp;
    __syncthreads();
    if (p == 0) {
        float kj = s_p3[0][0][j] + s_p3[1][0][j] + s_p3[2][0][j] + s_p3[3][0][j];
        s_cur[j] = kj;
        INS[t * D + j] = kj;
    } else if (p == 1) {
        s_v[j] = s_p3[0][1][j] + s_p3[1][1][j] + s_p3[2][1][j] + s_p3[3][1][j];
    } else if (p == 2) {
        Q[t * D + j] = s_p3[0][2][j] + s_p3[1][2][j] + s_p3[2][2][j] + s_p3[3][2][j];
    }
    __syncthreads();

    for (int l = 0; l < 4; l++) {
        const float* Wl = W_mem + l * DD;
        float yp = 0.f;
#pragma unroll 8
        for (int ii = 0; ii < 32; ii++) {
            int i = i0 + ii;
            yp += s_cur[i] * Wl[i * D + j];
        }
        s_part[p][j] = yp;
        __syncthreads();
        if (p == 0) {
            float y = s_part[0][j] + s_part[1][j] + s_part[2][j] + s_part[3][j];
            s_h[l][j] = y;
            if (l < 3) {
                float a = y * sigmoidf_(y);
                s_cur[j] = a;
                INS[(l + 1) * ND + t * D + j] = a;
            }
        }
        __syncthreads();
    }

    if (p == 0) {
        float e = -s_lr * (2.f / (float)D) * (s_h[3][j] - s_v[j]);
        ES[3 * ND + t * D + j] = e;
        s_cur[j] = e;
    }
    __syncthreads();

    // backward: e_{l-1}[j] = (sum_i e_l[i] * W_l[j][i]) * silu'(h_{l-1})
    // reads W_mem directly (row j, contiguous in i) -- no transpose needed
    for (int l = 3; l >= 1; l--) {
        const float4* wrow = (const float4*)(W_mem + l * DD + j * D + i0);
        const float4* cur4 = (const float4*)(s_cur + i0);
        float gp = 0.f;
#pragma unroll
        for (int ii = 0; ii < 8; ii++) {
            float4 w = wrow[ii];
            float4 c = cur4[ii];
            gp += c.x * w.x + c.y * w.y + c.z * w.z + c.w * w.w;
        }
        s_part[p][j] = gp;
        __syncthreads();
        if (p == 0) {
            float g = s_part[0][j] + s_part[1][j] + s_part[2][j] + s_part[3][j];
            float h = s_h[l - 1][j];
            float sg = sigmoidf_(h);
            float e2 = g * (sg * (1.f + h * (1.f - sg)));
            ES[(l - 1) * ND + t * D + j] = e2;
            s_cur[j] = e2;
        }
        __syncthreads();
    }
}

// ---------------- phase 2a: log-space prefix scans ----------------
__global__ __launch_bounds__(512) void k_logscan(
    const float* __restrict__ am, const float* __restrict__ dec,
    double* __restrict__ LA, double* __restrict__ LDp, int* __restrict__ NC)
{
    __shared__ double sa[N], sd[N];
    __shared__ int sn[N];
    const int t = threadIdx.x;
    float a = am[t];
    float d = dec[t];
    sa[t] = log((double)fmaxf(fabsf(a), 1e-38f));
    sd[t] = log((double)fmaxf(d, 1e-38f));
    sn[t] = (a < 0.f) ? 1 : 0;
    __syncthreads();
    for (int off = 1; off < N; off <<= 1) {
        double va = 0.0, vd = 0.0; int vn = 0;
        if (t >= off) { va = sa[t - off]; vd = sd[t - off]; vn = sn[t - off]; }
        __syncthreads();
        sa[t] += va; sd[t] += vd; sn[t] += vn;
        __syncthreads();
    }
    LA[t] = sa[t]; LDp[t] = sd[t]; NC[t] = sn[t];
}

// ---- phase 2c: betaP[z] partials, split-K<=4, A/D tiles built in-LDS ----
// grid (16,16,4), block 256. k_betared sums slabs.
__global__ __launch_bounds__(256) void k_betamm(
    const double* __restrict__ LA, const double* __restrict__ LDp,
    const int* __restrict__ NC, float* __restrict__ betaP)
{
    const int bs = blockIdx.x;
    const int bt = blockIdx.y;
    const int z  = blockIdx.z;
    if (bs > bt) return;
    const int span = bt - bs + 1;
    const int chunk = (span + 3) >> 2;
    const int kBeg = bs + z * chunk;
    const int kEnd = (kBeg + chunk < bt + 1) ? (kBeg + chunk) : (bt + 1);
    if (kBeg >= kEnd) return;

    __shared__ float sA[32 * 34];    // [u-k][s-col]
    __shared__ float sDT[32 * 34];   // [u-k][t-row]  (transposed on stage)

    const int tid = threadIdx.x;
    const int tx = tid & 15;
    const int ty = tid >> 4;
    float acc00 = 0.f, acc01 = 0.f, acc10 = 0.f, acc11 = 0.f;

    for (int kt = kBeg; kt < kEnd; kt++) {
        for (int i = tid; i < 1024; i += 256) {
            int r = i >> 5, c = i & 31;
            // A[u2][s2] from log-scan of am
            int u2 = kt * 32 + r, s2 = bs * 32 + c;
            float va = 0.f;
            if (s2 <= u2) {
                va = expf((float)(LA[u2] - LA[s2]));
                if ((NC[u2] - NC[s2]) & 1) va = -va;
            }
            sA[r * 34 + c] = va;
            // D[u1][s1] from log-scan of dec (stored transposed)
            int u1 = bt * 32 + r, s1 = kt * 32 + c;
            sDT[c * 34 + r] = (s1 <= u1) ? expf((float)(LDp[u1] - LDp[s1])) : 0.f;
        }
        __syncthreads();
#pragma unroll 8
        for (int k = 0; k < 32; k++) {
            float2 a = *(float2*)&sA[k * 34 + 2 * tx];
            float2 d = *(float2*)&sDT[k * 34 + 2 * ty];
            acc00 += d.x * a.x; acc01 += d.x * a.y;
            acc10 += d.y * a.x; acc11 += d.y * a.y;
        }
        __syncthreads();
    }
    float* bp = betaP + z * NN + (bt * 32 + 2 * ty) * N + bs * 32 + 2 * tx;
    *(float2*)bp       = make_float2(acc00, acc01);
    *(float2*)(bp + N) = make_float2(acc10, acc11);
}

// ---- phase 2d: beta = sum of valid slabs; zeros for upper triangle ----
__global__ __launch_bounds__(256) void k_betared(
    const float* __restrict__ betaP, float* __restrict__ beta)
{
    int idx4 = blockIdx.x * 256 + threadIdx.x;
    int t  = idx4 >> 7;
    int s0 = (idx4 & 127) * 4;
    int bt = t >> 5, bs = s0 >> 5;
    float4 v = make_float4(0.f, 0.f, 0.f, 0.f);
    if (bs <= bt) {
        int span = bt - bs + 1;
        int chunk = (span + 3) >> 2;
        int nz = (span + chunk - 1) / chunk;
        v = *(const float4*)(betaP + t * N + s0);
        for (int z = 1; z < nz; z++) {
            float4 u = *(const float4*)(betaP + z * NN + t * N + s0);
            v.x += u.x; v.y += u.y; v.z += u.z; v.w += u.w;
        }
    }
    *(float4*)(beta + t * N + s0) = v;
}

// ---------------- phase 3: one layer, 32-wide s-chunks, partial slabs -------
// grid (32, 18), block 256. z=0..16: 32-wide s-chunk (active iff 32z<=16r+15);
// z=17: X@W term -> slab 17. Plain stores, no atomics.
__global__ __launch_bounds__(256) void k_layer(
    const float* __restrict__ Xsrc, float* __restrict__ Pout,
    const float* __restrict__ Wl, const float* __restrict__ INSl,
    const float* __restrict__ ESl, const float* __restrict__ beta,
    int mode)
{
    const int r = blockIdx.x;
    const int z = blockIdx.y;
    const bool isW = (z == 17);
    if (!isW && 32 * z > 16 * r + 15) return;
    const int t0 = r * 16;
    const int lane = threadIdx.x;

    __shared__ __align__(16) float sX[16 * LSTR];
    __shared__ __align__(16) float sI[32 * LSTR];
    __shared__ __align__(16) float sE[32 * LSTR];
    __shared__ __align__(16) float sc[16 * CSTR];

    const int nzs = (r >> 1) + 1;   // valid s-slabs for this row tile
#pragma unroll
    for (int i = 0; i < 2; i++) {
        int f4 = lane + 256 * i;
        int row = f4 >> 5, c4 = f4 & 31;
        float4 v = ((const float4*)(Xsrc + t0 * D))[f4];
        if (mode) {
            for (int zz = 1; zz < nzs; zz++) {
                float4 u = ((const float4*)(Xsrc + zz * ND + t0 * D))[f4];
                v.x += u.x; v.y += u.y; v.z += u.z; v.w += u.w;
            }
            float4 w = ((const float4*)(Xsrc + 17 * ND + t0 * D))[f4];
            v.x += w.x; v.y += w.y; v.z += w.z; v.w += w.w;
            v.x = v.x * sigmoidf_(v.x); v.y = v.y * sigmoidf_(v.y);
            v.z = v.z * sigmoidf_(v.z); v.w = v.w * sigmoidf_(v.w);
        }
        *(float4*)(sX + row * LSTR + c4 * 4) = v;
    }

    const int ti  = lane >> 4;
    const int q15 = lane & 15;
    const int j8  = q15 * 8;

    if (isW) {
        __syncthreads();
        float acc[8];
#pragma unroll
        for (int b = 0; b < 8; b++) acc[b] = 0.f;
#pragma unroll 4
        for (int k = 0; k < D; k++) {
            float4 w0 = *(const float4*)(Wl + k * D + j8);
            float4 w1 = *(const float4*)(Wl + k * D + j8 + 4);
            float xv = sX[ti * LSTR + k];
            acc[0] += xv * w0.x; acc[1] += xv * w0.y;
            acc[2] += xv * w0.z; acc[3] += xv * w0.w;
            acc[4] += xv * w1.x; acc[5] += xv * w1.y;
            acc[6] += xv * w1.z; acc[7] += xv * w1.w;
        }
        float* yp = Pout + 17 * ND + (t0 + ti) * D + j8;
        *(float4*)yp       = make_float4(acc[0], acc[1], acc[2], acc[3]);
        *(float4*)(yp + 4) = make_float4(acc[4], acc[5], acc[6], acc[7]);
        return;
    }

    const int s0 = z * 32;
#pragma unroll
    for (int i = 0; i < 4; i++) {
        int f4 = lane + 256 * i;
        int row = f4 >> 5, c4 = f4 & 31;
        float4 a = ((const float4*)(INSl + s0 * D))[f4];
        float4 b = ((const float4*)(ESl + s0 * D))[f4];
        *(float4*)(sI + row * LSTR + c4 * 4) = a;
        *(float4*)(sE + row * LSTR + c4 * 4) = b;
    }
    const int si0 = q15 * 2;
    float b0 = beta[(t0 + ti) * N + s0 + si0];
    float b1 = beta[(t0 + ti) * N + s0 + si0 + 1];
    __syncthreads();

    // GEMM1: c[ti][si0], c[ti][si0+1]
    float g0 = 0.f, g1 = 0.f;
#pragma unroll 8
    for (int k4 = 0; k4 < D; k4 += 4) {
        float4 a  = *(float4*)(sX + ti * LSTR + k4);
        float4 p0 = *(float4*)(sI + si0 * LSTR + k4);
        float4 p1 = *(float4*)(sI + (si0 + 1) * LSTR + k4);
        g0 += a.x * p0.x + a.y * p0.y + a.z * p0.z + a.w * p0.w;
        g1 += a.x * p1.x + a.y * p1.y + a.z * p1.z + a.w * p1.w;
    }
    sc[ti * CSTR + si0]     = g0 * b0;
    sc[ti * CSTR + si0 + 1] = g1 * b1;
    __syncthreads();

    // GEMM2: P[ti][j8..j8+7] = sum_s c[ti][s] * E[s][j8..]
    float acc[8];
#pragma unroll
    for (int b = 0; b < 8; b++) acc[b] = 0.f;
#pragma unroll 8
    for (int s = 0; s < 32; s++) {
        float cv = sc[ti * CSTR + s];
        float4 e0 = *(float4*)(sE + s * LSTR + j8);
        float4 e1 = *(float4*)(sE + s * LSTR + j8 + 4);
        acc[0] += cv * e0.x; acc[1] += cv * e0.y;
        acc[2] += cv * e0.z; acc[3] += cv * e0.w;
        acc[4] += cv * e1.x; acc[5] += cv * e1.y;
        acc[6] += cv * e1.z; acc[7] += cv * e1.w;
    }
    float* yp = Pout + z * ND + (t0 + ti) * D + j8;
    *(float4*)yp       = make_float4(acc[0], acc[1], acc[2], acc[3]);
    *(float4*)(yp + 4) = make_float4(acc[4], acc[5], acc[6], acc[7]);
}

// ---------------- final reduce: out = sum of valid slabs (no silu) ----------
__global__ __launch_bounds__(256) void k_reduce(
    const float* __restrict__ P, float* __restrict__ out)
{
    int f4 = blockIdx.x * 256 + threadIdx.x;
    int t = f4 >> 5;
    int r = t >> 4;
    int nzs = (r >> 1) + 1;
    float4 v = ((const float4*)P)[f4];
    for (int zz = 1; zz < nzs; zz++) {
        float4 u = ((const float4*)(P + zz * ND))[f4];
        v.x += u.x; v.y += u.y; v.z += u.z; v.w += u.w;
    }
    float4 w = ((const float4*)(P + 17 * ND))[f4];
    v.x += w.x; v.y += w.y; v.z += w.z; v.w += w.w;
    ((float4*)out)[f4] = v;
}

extern "C" void kernel_launch(void* const* d_in, const int* in_sizes, int n_in,
                              void* d_out, int out_size, void* d_ws, size_t ws_size,
                              hipStream_t stream) {
    const float* seq     = (const float*)d_in[0];
    const float* W_mem   = (const float*)d_in[1];
    const float* W_q     = (const float*)d_in[2];
    const float* W_kv    = (const float*)d_in[3];
    const float* W_mom   = (const float*)d_in[4];
    const float* W_step  = (const float*)d_in[5];
    const float* W_decay = (const float*)d_in[6];
    float* out = (float*)d_out;

    float* ws   = (float*)d_ws;
    float* am   = ws;                  // N
    float* dec  = am + N;              // N
    float* Q    = dec + N;             // N*D
    float* INS  = Q + ND;              // 4*N*D
    float* ES   = INS + 4 * ND;        // 4*N*D
    float* beta = ES + 4 * ND;         // N*N
    float* Pa   = beta + NN;           // NSLAB*N*D
    float* Pb   = Pa + NSLAB * ND;     // NSLAB*N*D
    double* LA  = (double*)(Pb + NSLAB * ND);
    double* LDp = LA + N;
    int* NC     = (int*)(LDp + N);
    float* betaP = Pa;                 // 4*N*N aliases Pa (dead until layer 0 writes)

    k_phase1<<<N, 512, 0, stream>>>(seq, W_mem, W_q, W_kv, W_mom, W_step, W_decay,
                                    Q, INS, ES, am, dec);
    k_logscan<<<1, N, 0, stream>>>(am, dec, LA, LDp, NC);
    dim3 mmgrid(N / 32, N / 32, 4);
    k_betamm<<<mmgrid, 256, 0, stream>>>(LA, LDp, NC, betaP);
    k_betared<<<NN / 4 / 256, 256, 0, stream>>>(betaP, beta);

    dim3 lgrid(32, 18);
    k_layer<<<lgrid, 256, 0, stream>>>(Q,  Pa, W_mem,          INS,          ES,          beta, 0);
    k_layer<<<lgrid, 256, 0, stream>>>(Pa, Pb, W_mem + DD,     INS + ND,     ES + ND,     beta, 1);
    k_layer<<<lgrid, 256, 0, stream>>>(Pb, Pa, W_mem + 2 * DD, INS + 2 * ND, ES + 2 * ND, beta, 1);
    k_layer<<<lgrid, 256, 0, stream>>>(Pa, Pb, W_mem + 3 * DD, INS + 3 * ND, ES + 3 * ND, beta, 1);
    k_reduce<<<64, 256, 0, stream>>>(Pb, out);
}

// Round 9
// 163.170 us; speedup vs baseline: 1.2397x; 1.2397x over previous
//
#include <hip/hip_runtime.h>
#include <hip/hip_bf16.h>
#include <math.h>

#define N 512
#define NN (N*N)
#define D 128
#define DD (D*D)
#define ND (N*D)
#define LSTR 132   // LDS row stride (floats) for 128-wide tiles
#define CSTR 68    // LDS row stride for 64-wide c tile

__device__ __forceinline__ float sigmoidf_(float x) { return 1.f / (1.f + expf(-x)); }

// ---------------- transpose W_mem layers 1..3 for backward ----------------
__global__ void k_transpose(const float* __restrict__ W_mem, float* __restrict__ WT) {
    int idx = blockIdx.x * 256 + threadIdx.x;
    int l = idx / DD;
    int r = idx % DD;
    int i = r / D;
    int j = r % D;
    WT[idx] = W_mem[(l + 1) * DD + j * D + i];
}

// ---------------- phase 1: per-token scalars, k/v/q, MLP fwd+bwd ----------------
__global__ __launch_bounds__(512) void k_phase1(
    const float* __restrict__ seq, const float* __restrict__ W_mem,
    const float* __restrict__ W_q, const float* __restrict__ W_kv,
    const float* __restrict__ W_mom, const float* __restrict__ W_step,
    const float* __restrict__ W_decay, const float* __restrict__ WT,
    float* __restrict__ Q, float* __restrict__ INS, float* __restrict__ ES,
    float* __restrict__ am, float* __restrict__ dec)
{
    __shared__ float s_seq[D], s_v[D], s_cur[D];
    __shared__ float s_h[4][D];
    __shared__ float s_part[4][D];
    __shared__ float s_p3[4][3][D];
    __shared__ float s_red[8];
    __shared__ float s_lr;

    const int t = blockIdx.x;
    const int tid = threadIdx.x;
    const int j = tid & 127;
    const int p = tid >> 7;
    const int i0 = p * 32;

    if (p == 0) s_seq[j] = seq[t * D + j];
    __syncthreads();

    float ps = 0.f;
    if (p == 1) ps = s_seq[j] * W_step[j];
    else if (p == 2) ps = s_seq[j] * W_mom[j];
    else if (p == 3) ps = s_seq[j] * W_decay[j];
#pragma unroll
    for (int off = 32; off > 0; off >>= 1) ps += __shfl_down(ps, off);
    if ((tid & 63) == 0) s_red[tid >> 6] = ps;
    __syncthreads();
    if (tid == 0) s_lr = s_red[2] + s_red[3];
    else if (tid == 1) am[t] = s_red[4] + s_red[5];
    else if (tid == 2) dec[t] = 1.f - sigmoidf_(s_red[6] + s_red[7]);

    float kp = 0.f, vp = 0.f, qp = 0.f;
#pragma unroll 8
    for (int ii = 0; ii < 32; ii++) {
        int i = i0 + ii;
        float si = s_seq[i];
        kp += si * W_kv[i * 256 + j];
        vp += si * W_kv[i * 256 + 128 + j];
        qp += si * W_q[i * 128 + j];
    }
    s_p3[p][0][j] = kp; s_p3[p][1][j] = vp; s_p3[p][2][j] = qp;
    __syncthreads();
    if (p == 0) {
        float kj = s_p3[0][0][j] + s_p3[1][0][j] + s_p3[2][0][j] + s_p3[3][0][j];
        s_cur[j] = kj;
        INS[t * D + j] = kj;
    } else if (p == 1) {
        s_v[j] = s_p3[0][1][j] + s_p3[1][1][j] + s_p3[2][1][j] + s_p3[3][1][j];
    } else if (p == 2) {
        Q[t * D + j] = s_p3[0][2][j] + s_p3[1][2][j] + s_p3[2][2][j] + s_p3[3][2][j];
    }
    __syncthreads();

    for (int l = 0; l < 4; l++) {
        const float* Wl = W_mem + l * DD;
        float yp = 0.f;
#pragma unroll 8
        for (int ii = 0; ii < 32; ii++) {
            int i = i0 + ii;
            yp += s_cur[i] * Wl[i * D + j];
        }
        s_part[p][j] = yp;
        __syncthreads();
        if (p == 0) {
            float y = s_part[0][j] + s_part[1][j] + s_part[2][j] + s_part[3][j];
            s_h[l][j] = y;
            if (l < 3) {
                float a = y * sigmoidf_(y);
                s_cur[j] = a;
                INS[(l + 1) * ND + t * D + j] = a;
            }
        }
        __syncthreads();
    }

    if (p == 0) {
        float e = -s_lr * (2.f / (float)D) * (s_h[3][j] - s_v[j]);
        ES[3 * ND + t * D + j] = e;
        s_cur[j] = e;
    }
    __syncthreads();

    for (int l = 3; l >= 1; l--) {
        const float* Wt = WT + (l - 1) * DD;
        float gp = 0.f;
#pragma unroll 8
        for (int ii = 0; ii < 32; ii++) {
            int i = i0 + ii;
            gp += s_cur[i] * Wt[i * D + j];
        }
        s_part[p][j] = gp;
        __syncthreads();
        if (p == 0) {
            float g = s_part[0][j] + s_part[1][j] + s_part[2][j] + s_part[3][j];
            float h = s_h[l - 1][j];
            float sg = sigmoidf_(h);
            float e2 = g * (sg * (1.f + h * (1.f - sg)));
            ES[(l - 1) * ND + t * D + j] = e2;
            s_cur[j] = e2;
        }
        __syncthreads();
    }
}

// ---------------- phase 2a: log-space prefix scans ----------------
__global__ __launch_bounds__(512) void k_logscan(
    const float* __restrict__ am, const float* __restrict__ dec,
    double* __restrict__ LA, double* __restrict__ LDp, int* __restrict__ NC)
{
    __shared__ double sa[N], sd[N];
    __shared__ int sn[N];
    const int t = threadIdx.x;
    float a = am[t];
    float d = dec[t];
    sa[t] = log((double)fmaxf(fabsf(a), 1e-38f));
    sd[t] = log((double)fmaxf(d, 1e-38f));
    sn[t] = (a < 0.f) ? 1 : 0;
    __syncthreads();
    for (int off = 1; off < N; off <<= 1) {
        double va = 0.0, vd = 0.0; int vn = 0;
        if (t >= off) { va = sa[t - off]; vd = sd[t - off]; vn = sn[t - off]; }
        __syncthreads();
        sa[t] += va; sd[t] += vd; sn[t] += vn;
        __syncthreads();
    }
    LA[t] = sa[t]; LDp[t] = sd[t]; NC[t] = sn[t];
}

// ---------------- phase 2b: build L_A, L_D ----------------
__global__ __launch_bounds__(256) void k_build(
    const double* __restrict__ LA, const double* __restrict__ LDp,
    const int* __restrict__ NC,
    float* __restrict__ Amat, float* __restrict__ Dmat)
{
    int idx = blockIdx.x * 256 + threadIdx.x;
    int u = idx >> 9;
    int s = idx & (N - 1);
    float va = 0.f, vd = 0.f;
    if (s <= u) {
        va = expf((float)(LA[u] - LA[s]));
        if ((NC[u] - NC[s]) & 1) va = -va;
        vd = expf((float)(LDp[u] - LDp[s]));
    }
    Amat[idx] = va;
    Dmat[idx] = vd;
}

// ---- phase 2c: betaP[z] partial products, split-K<=4 tiles, 2x2 float2 ----
__global__ __launch_bounds__(256) void k_betamm(
    const float* __restrict__ Dmat, const float* __restrict__ Amat,
    float* __restrict__ betaP)
{
    const int bs = blockIdx.x;
    const int bt = blockIdx.y;
    const int z  = blockIdx.z;
    if (bs > bt) return;
    const int span = bt - bs + 1;
    const int chunk = (span + 3) >> 2;
    const int kBeg = bs + z * chunk;
    const int kEnd = (kBeg + chunk < bt + 1) ? (kBeg + chunk) : (bt + 1);
    if (kBeg >= kEnd) return;

    __shared__ float sA[32 * 34];    // [u-k][s-col]
    __shared__ float sDT[32 * 34];   // [u-k][t-row]  (transposed on stage)

    const int tid = threadIdx.x;
    const int tx = tid & 15;
    const int ty = tid >> 4;
    float acc00 = 0.f, acc01 = 0.f, acc10 = 0.f, acc11 = 0.f;

    for (int kt = kBeg; kt < kEnd; kt++) {
        for (int i = tid; i < 1024; i += 256) {
            int r = i >> 5, c = i & 31;
            sA[r * 34 + c]  = Amat[(kt * 32 + r) * N + bs * 32 + c];
            sDT[c * 34 + r] = Dmat[(bt * 32 + r) * N + kt * 32 + c];
        }
        __syncthreads();
#pragma unroll 8
        for (int k = 0; k < 32; k++) {
            float2 a = *(float2*)&sA[k * 34 + 2 * tx];
            float2 d = *(float2*)&sDT[k * 34 + 2 * ty];
            acc00 += d.x * a.x; acc01 += d.x * a.y;
            acc10 += d.y * a.x; acc11 += d.y * a.y;
        }
        __syncthreads();
    }
    float* bp = betaP + z * NN + (bt * 32 + 2 * ty) * N + bs * 32 + 2 * tx;
    *(float2*)bp       = make_float2(acc00, acc01);
    *(float2*)(bp + N) = make_float2(acc10, acc11);
}

// ---- phase 2d: beta = sum of valid slabs; zeros for upper triangle ----
__global__ __launch_bounds__(256) void k_betared(
    const float* __restrict__ betaP, float* __restrict__ beta)
{
    int idx4 = blockIdx.x * 256 + threadIdx.x;
    int t  = idx4 >> 7;
    int s0 = (idx4 & 127) * 4;
    int bt = t >> 5, bs = s0 >> 5;
    float4 v = make_float4(0.f, 0.f, 0.f, 0.f);
    if (bs <= bt) {
        int span = bt - bs + 1;
        int chunk = (span + 3) >> 2;
        int nz = (span + chunk - 1) / chunk;
        v = *(const float4*)(betaP + t * N + s0);
        for (int z = 1; z < nz; z++) {
            float4 u = *(const float4*)(betaP + z * NN + t * N + s0);
            v.x += u.x; v.y += u.y; v.z += u.z; v.w += u.w;
        }
    }
    *(float4*)(beta + t * N + s0) = v;
}

// ---------------- phase 3: one layer, 64-wide s-chunks, v2 register tiling --
// grid (32, 9), block 256. z=0..7: 64-wide s-chunk (active iff 4z<=r);
// z=8: X@W term -> slab 8. Plain stores into per-(r,z) slabs, no atomics.
// GEMM1: full 64-row sI staged once, 2x2 tile (tokens {2rp,2rp+1} x s {sp,sp+32}).
// GEMM2: 2 sub-passes over sE (32 rows), 2-token x 4-col tile.
__global__ __launch_bounds__(256) void k_layer(
    const float* __restrict__ Xsrc, float* __restrict__ Pout,
    const float* __restrict__ Wl, const float* __restrict__ INSl,
    const float* __restrict__ ESl, const float* __restrict__ beta,
    int mode)
{
    const int r = blockIdx.x;
    const int z = blockIdx.y;
    const bool isW = (z == 8);
    if (!isW && 4 * z > r) return;
    const int t0 = r * 16;
    const int lane = threadIdx.x;

    __shared__ __align__(16) float sX[16 * LSTR];   //  8448 B
    __shared__ __align__(16) float sI[64 * LSTR];   // 33792 B
    __shared__ __align__(16) float sE[32 * LSTR];   // 16896 B
    __shared__ __align__(16) float sc[16 * CSTR];   //  4352 B  (total 63488)

    // ---- stage X tile (16x128 = 512 float4, 2 per thread) ----
    const int nzs = (r >> 2) + 1;
#pragma unroll
    for (int i = 0; i < 2; i++) {
        int f4 = lane + 256 * i;
        int row = f4 >> 5, c4 = f4 & 31;
        float4 v = ((const float4*)(Xsrc + t0 * D))[f4];
        if (mode) {
            for (int zz = 1; zz < nzs; zz++) {
                float4 u = ((const float4*)(Xsrc + zz * ND + t0 * D))[f4];
                v.x += u.x; v.y += u.y; v.z += u.z; v.w += u.w;
            }
            float4 w = ((const float4*)(Xsrc + 8 * ND + t0 * D))[f4];
            v.x += w.x; v.y += w.y; v.z += w.z; v.w += w.w;
            v.x = v.x * sigmoidf_(v.x); v.y = v.y * sigmoidf_(v.y);
            v.z = v.z * sigmoidf_(v.z); v.w = v.w * sigmoidf_(v.w);
        }
        *(float4*)(sX + row * LSTR + c4 * 4) = v;
    }

    if (isW) {
        __syncthreads();
        const int ti  = lane >> 4;
        const int j8  = (lane & 15) * 8;
        float acc[8];
#pragma unroll
        for (int b = 0; b < 8; b++) acc[b] = 0.f;
#pragma unroll 4
        for (int k = 0; k < D; k++) {
            float4 w0 = *(const float4*)(Wl + k * D + j8);
            float4 w1 = *(const float4*)(Wl + k * D + j8 + 4);
            float xv = sX[ti * LSTR + k];
            acc[0] += xv * w0.x; acc[1] += xv * w0.y;
            acc[2] += xv * w0.z; acc[3] += xv * w0.w;
            acc[4] += xv * w1.x; acc[5] += xv * w1.y;
            acc[6] += xv * w1.z; acc[7] += xv * w1.w;
        }
        float* yp = Pout + 8 * ND + (t0 + ti) * D + j8;
        *(float4*)yp       = make_float4(acc[0], acc[1], acc[2], acc[3]);
        *(float4*)(yp + 4) = make_float4(acc[4], acc[5], acc[6], acc[7]);
        return;
    }

    const int s0 = z * 64;

    // ---- stage full sI (64 x 128 = 2048 float4, 8/thread) ----
#pragma unroll
    for (int i = 0; i < 8; i++) {
        int f4 = lane + 256 * i;
        int row = f4 >> 5, c4 = f4 & 31;
        float4 a = ((const float4*)(INSl + s0 * D))[f4];
        *(float4*)(sI + row * LSTR + c4 * 4) = a;
    }

    // ---- GEMM1: c[2rp..2rp+1][sp, sp+32] (2x2 tile) ----
    const int rp = lane >> 5;        // 0..7 -> tokens 2rp, 2rp+1
    const int sp = lane & 31;        // s cols sp and sp+32
    // beta prefetch (4 scalars), overlaps staging latency
    float b00 = beta[(t0 + 2 * rp) * N + s0 + sp];
    float b01 = beta[(t0 + 2 * rp) * N + s0 + sp + 32];
    float b10 = beta[(t0 + 2 * rp + 1) * N + s0 + sp];
    float b11 = beta[(t0 + 2 * rp + 1) * N + s0 + sp + 32];
    __syncthreads();

    float g00 = 0.f, g01 = 0.f, g10 = 0.f, g11 = 0.f;
#pragma unroll 8
    for (int k4 = 0; k4 < D; k4 += 4) {
        float4 a0 = *(float4*)(sX + (2 * rp) * LSTR + k4);
        float4 a1 = *(float4*)(sX + (2 * rp + 1) * LSTR + k4);
        float4 p0 = *(float4*)(sI + sp * LSTR + k4);
        float4 p1 = *(float4*)(sI + (sp + 32) * LSTR + k4);
        g00 += a0.x * p0.x + a0.y * p0.y + a0.z * p0.z + a0.w * p0.w;
        g01 += a0.x * p1.x + a0.y * p1.y + a0.z * p1.z + a0.w * p1.w;
        g10 += a1.x * p0.x + a1.y * p0.y + a1.z * p0.z + a1.w * p0.w;
        g11 += a1.x * p1.x + a1.y * p1.y + a1.z * p1.z + a1.w * p1.w;
    }
    sc[(2 * rp) * CSTR + sp]          = g00 * b00;
    sc[(2 * rp) * CSTR + sp + 32]     = g01 * b01;
    sc[(2 * rp + 1) * CSTR + sp]      = g10 * b10;
    sc[(2 * rp + 1) * CSTR + sp + 32] = g11 * b11;

    // ---- GEMM2: 2 sub-passes, 2-token x 4-col tile ----
    const int tp = lane >> 5;        // 0..7 -> tokens tp, tp+8
    const int jc = (lane & 31) * 4;  // 4-col group
    float acc[2][4];
#pragma unroll
    for (int a = 0; a < 2; a++)
#pragma unroll
        for (int b = 0; b < 4; b++) acc[a][b] = 0.f;

    for (int sub = 0; sub < 2; sub++) {
        __syncthreads();   // sc ready (sub 0) / previous sE reads done (sub 1)
#pragma unroll
        for (int i = 0; i < 4; i++) {
            int f4 = lane + 256 * i;
            int row = f4 >> 5, c4 = f4 & 31;
            float4 b = ((const float4*)(ESl + (s0 + sub * 32) * D))[f4];
            *(float4*)(sE + row * LSTR + c4 * 4) = b;
        }
        __syncthreads();
        const float* scp0 = sc + tp * CSTR + sub * 32;
        const float* scp1 = sc + (tp + 8) * CSTR + sub * 32;
#pragma unroll 8
        for (int s = 0; s < 32; s++) {
            float c0 = scp0[s];
            float c1 = scp1[s];
            float4 e = *(float4*)(sE + s * LSTR + jc);
            acc[0][0] += c0 * e.x; acc[0][1] += c0 * e.y;
            acc[0][2] += c0 * e.z; acc[0][3] += c0 * e.w;
            acc[1][0] += c1 * e.x; acc[1][1] += c1 * e.y;
            acc[1][2] += c1 * e.z; acc[1][3] += c1 * e.w;
        }
    }

    float* yp0 = Pout + z * ND + (t0 + tp) * D + jc;
    float* yp1 = Pout + z * ND + (t0 + tp + 8) * D + jc;
    *(float4*)yp0 = make_float4(acc[0][0], acc[0][1], acc[0][2], acc[0][3]);
    *(float4*)yp1 = make_float4(acc[1][0], acc[1][1], acc[1][2], acc[1][3]);
}

// ---------------- final reduce: out = sum of valid slabs (no silu) ----------
__global__ __launch_bounds__(256) void k_reduce(
    const float* __restrict__ P, float* __restrict__ out)
{
    int f4 = blockIdx.x * 256 + threadIdx.x;
    int t = f4 >> 5;
    int r = t >> 4;
    int nzs = (r >> 2) + 1;
    float4 v = ((const float4*)P)[f4];
    for (int zz = 1; zz < nzs; zz++) {
        float4 u = ((const float4*)(P + zz * ND))[f4];
        v.x += u.x; v.y += u.y; v.z += u.z; v.w += u.w;
    }
    float4 w = ((const float4*)(P + 8 * ND))[f4];
    v.x += w.x; v.y += w.y; v.z += w.z; v.w += w.w;
    ((float4*)out)[f4] = v;
}

extern "C" void kernel_launch(void* const* d_in, const int* in_sizes, int n_in,
                              void* d_out, int out_size, void* d_ws, size_t ws_size,
                              hipStream_t stream) {
    const float* seq     = (const float*)d_in[0];
    const float* W_mem   = (const float*)d_in[1];
    const float* W_q     = (const float*)d_in[2];
    const float* W_kv    = (const float*)d_in[3];
    const float* W_mom   = (const float*)d_in[4];
    const float* W_step  = (const float*)d_in[5];
    const float* W_decay = (const float*)d_in[6];
    float* out = (float*)d_out;

    float* ws   = (float*)d_ws;
    float* am   = ws;                  // N
    float* dec  = am + N;              // N
    float* Q    = dec + N;             // N*D
    float* INS  = Q + ND;              // 4*N*D
    float* ES   = INS + 4 * ND;        // 4*N*D
    float* beta = ES + 4 * ND;         // N*N
    float* WT   = beta + NN;           // 3*D*D
    float* Amat = WT + 3 * DD;         // N*N
    float* Dmat = Amat + NN;           // N*N
    float* Pa   = Dmat + NN;           // 9*N*D
    float* Pb   = Pa + 9 * ND;         // 9*N*D
    double* LA  = (double*)(Pb + 9 * ND);
    double* LDp = LA + N;
    int* NC     = (int*)(LDp + N);
    float* betaP = Pa;                 // 4*N*N aliases Pa+Pb (dead until layer 0)

    k_transpose<<<192, 256, 0, stream>>>(W_mem, WT);
    k_phase1<<<N, 512, 0, stream>>>(seq, W_mem, W_q, W_kv, W_mom, W_step, W_decay,
                                    WT, Q, INS, ES, am, dec);
    k_logscan<<<1, N, 0, stream>>>(am, dec, LA, LDp, NC);
    k_build<<<(NN) / 256, 256, 0, stream>>>(LA, LDp, NC, Amat, Dmat);
    dim3 mmgrid(N / 32, N / 32, 4);
    k_betamm<<<mmgrid, 256, 0, stream>>>(Dmat, Amat, betaP);
    k_betared<<<NN / 4 / 256, 256, 0, stream>>>(betaP, beta);

    dim3 lgrid(32, 9);
    k_layer<<<lgrid, 256, 0, stream>>>(Q,  Pa, W_mem,          INS,          ES,          beta, 0);
    k_layer<<<lgrid, 256, 0, stream>>>(Pa, Pb, W_mem + DD,     INS + ND,     ES + ND,     beta, 1);
    k_layer<<<lgrid, 256, 0, stream>>>(Pb, Pa, W_mem + 2 * DD, INS + 2 * ND, ES + 2 * ND, beta, 1);
    k_layer<<<lgrid, 256, 0, stream>>>(Pa, Pb, W_mem + 3 * DD, INS + 3 * ND, ES + 3 * ND, beta, 1);
    k_reduce<<<64, 256, 0, stream>>>(Pb, out);
}